// Round 2
// baseline (370.359 us; speedup 1.0000x reference)
//
#include <hip/hip_runtime.h>
#include <math.h>
#include <stdint.h>

#define NN 200000   // nodes
#define DD 256      // feature dim
#define BB 256      // batch rows of adj
#define SS 512      // output samples
#define HH 51200000u // 256*NN, half-size of the 512*NN flat gumbel array

// PRNG bit-layout variant for jax.random.categorical(key(1), ...):
//  1 = threefry_partitionable (modern JAX default): elem i -> tf(0, i), bits = out0 ^ out1
//  2 = legacy split-iota: i<H -> out0 of tf(i, i+H); else out1 of tf(i-H, i)
//  3 = partitionable out0-only (tried round 1: WRONG, support absmax 568)
#define PRNG_VARIANT 1

typedef unsigned int u32;
typedef unsigned long long u64;

// ---------------- threefry2x32, key = (0,1)  (jax.random.key(1)) ----------------
__device__ __forceinline__ uint2 tf2x32(u32 x0, u32 x1) {
  const u32 ks0 = 0u, ks1 = 1u, ks2 = 0x1BD11BDBu; // 0x1BD11BDA ^ 0 ^ 1
  x0 += ks0; x1 += ks1;
#define TFR(r) { x0 += x1; x1 = (x1 << (r)) | (x1 >> (32 - (r))); x1 ^= x0; }
  TFR(13) TFR(15) TFR(26) TFR(6)
  x0 += ks1; x1 += ks2 + 1u;
  TFR(17) TFR(29) TFR(16) TFR(24)
  x0 += ks2; x1 += ks0 + 2u;
  TFR(13) TFR(15) TFR(26) TFR(6)
  x0 += ks0; x1 += ks1 + 3u;
  TFR(17) TFR(29) TFR(16) TFR(24)
  x0 += ks1; x1 += ks2 + 4u;
  TFR(13) TFR(15) TFR(26) TFR(6)
  x0 += ks2; x1 += ks0 + 5u;
#undef TFR
  return make_uint2(x0, x1);
}

// exact JAX uniform(tiny,1) -> gumbel chain in f32
__device__ __forceinline__ float gumbel_from_bits(u32 bits) {
  const float TINY = 1.17549435e-38f;
  float f = __uint_as_float((bits >> 9) | 0x3f800000u) - 1.0f; // [0,1)
  float x = f + TINY;           // matches floats*(1.0f)+tiny
  x = fmaxf(TINY, x);
  return -logf(-logf(x));
}

// ---------------- kernels ----------------
__global__ void k_init(float* scal, float* means) {
  int t = threadIdx.x;
  means[t] = 0.0f;
  if (t < 16) scal[t] = 0.0f; // also zeroes the int counters aliased at scal[2],scal[3]
}

// one wave per row: dot(feat[row], w). rows==nullptr -> row=wave (fw2); else gathered (hw1)
__global__ __launch_bounds__(256) void k_dotw(const float* __restrict__ feat,
                                              const float* __restrict__ w,
                                              float* __restrict__ outv,
                                              const int* __restrict__ rows,
                                              int nrows) {
  int wave = blockIdx.x * 4 + (threadIdx.x >> 6);
  int lane = threadIdx.x & 63;
  if (wave >= nrows) return;
  int row = rows ? rows[wave] : wave;
  float4 f4 = ((const float4*)(feat + (size_t)row * DD))[lane];
  float4 w4 = ((const float4*)w)[lane];
  float d = f4.x * w4.x + f4.y * w4.y + f4.z * w4.z + f4.w * w4.w;
#pragma unroll
  for (int off = 32; off; off >>= 1) d += __shfl_down(d, off);
  if (lane == 0) outv[wave] = d;
}

// per-column pass over adj: col_sum (mask), s1[n] = sum_b adj*relu(hw1[b]+fw2[n]+1)
// builds compacted mask list and valid (s1>0) list via wave-aggregated atomics
__global__ __launch_bounds__(256) void k_adj(const float* __restrict__ adj,
                                             const float* __restrict__ fw2,
                                             const float* __restrict__ hw1,
                                             float* __restrict__ s1,
                                             int* __restrict__ mlist,
                                             int* __restrict__ vidx,
                                             int* __restrict__ counters) {
  __shared__ float hs[BB];
  hs[threadIdx.x] = hw1[threadIdx.x];
  __syncthreads();
  int n = blockIdx.x * 256 + threadIdx.x;
  bool on = (n < NN);
  float cs = 0.0f, ss = 0.0f;
  if (on) {
    float fv = fw2[n];
    const float* p = adj + n;
#pragma unroll 4
    for (int b = 0; b < BB; ++b) {
      float a = p[(size_t)b * NN];
      cs += a;
      if (a > 0.0f) ss += a * fmaxf(hs[b] + fv + 1.0f, 0.0f);
    }
    s1[n] = ss;
  }
  int lane = threadIdx.x & 63;
  // append to mask list
  {
    bool pred = on && (cs > 0.0f);
    u64 bm = __ballot(pred);
    int cnt = __popcll(bm);
    if (cnt) {
      int leader = __ffsll((u64)bm) - 1;
      int base = 0;
      if (lane == leader) base = atomicAdd(&counters[0], cnt);
      base = __shfl(base, leader);
      if (pred) mlist[base + __popcll(bm & ((1ull << lane) - 1ull))] = n;
    }
  }
  // append to valid (p1>0) list
  {
    bool pred = on && (ss > 0.0f);
    u64 bm = __ballot(pred);
    int cnt = __popcll(bm);
    if (cnt) {
      int leader = __ffsll((u64)bm) - 1;
      int base = 0;
      if (lane == leader) base = atomicAdd(&counters[1], cnt);
      base = __shfl(base, leader);
      if (pred) vidx[base + __popcll(bm & ((1ull << lane) - 1ull))] = n;
    }
  }
}

// p1 = s1/num_neis (in place), vlog[j] = log(p1), sum_p1
__global__ void k_fin(float* __restrict__ s1p1, float* __restrict__ vlog,
                      const int* __restrict__ vidx, const int* __restrict__ counters,
                      float* __restrict__ scal) {
  int nv = counters[1];
  float nnf = (float)counters[0];
  float local = 0.0f;
  for (int j = blockIdx.x * blockDim.x + threadIdx.x; j < nv; j += gridDim.x * blockDim.x) {
    int n = vidx[j];
    float p = s1p1[n] / nnf;
    s1p1[n] = p;
    vlog[j] = logf(p);
    local += p;
  }
#pragma unroll
  for (int off = 32; off; off >>= 1) local += __shfl_down(local, off);
  if ((threadIdx.x & 63) == 0) atomicAdd(&scal[0], local);
}

// means[d] = sum over masked rows of feat[row][d]
__global__ void k_means(const float* __restrict__ feat, const int* __restrict__ mlist,
                        const int* __restrict__ counters, float* __restrict__ means) {
  int nm = counters[0];
  float acc = 0.0f;
  for (int j = blockIdx.x; j < nm; j += gridDim.x)
    acc += feat[(size_t)mlist[j] * DD + threadIdx.x];
  atomicAdd(&means[threadIdx.x], acc);
}

// loss_acc = sum over valid rows of p_u * ||f[row]-means||^2
__global__ void k_loss(const float* __restrict__ feat, const float* __restrict__ means,
                       const float* __restrict__ s1p1, const int* __restrict__ vidx,
                       const int* __restrict__ counters, float* __restrict__ scal) {
  __shared__ float ms[DD];
  ms[threadIdx.x] = means[threadIdx.x];
  __syncthreads();
  int nv = counters[1];
  float spu = scal[0];
  int gw = blockIdx.x * 4 + (threadIdx.x >> 6);
  int tw = gridDim.x * 4;
  int lane = threadIdx.x & 63;
  float wacc = 0.0f;
  for (int j = gw; j < nv; j += tw) {
    int r = vidx[j];
    float4 f4 = ((const float4*)(feat + (size_t)r * DD))[lane];
    float4 m4 = ((const float4*)ms)[lane];
    float dx = f4.x - m4.x, dy = f4.y - m4.y, dz = f4.z - m4.z, dw = f4.w - m4.w;
    float val = dx * dx + dy * dy + dz * dz + dw * dw;
#pragma unroll
    for (int off = 32; off; off >>= 1) val += __shfl_down(val, off);
    if (lane == 0) wacc += (s1p1[r] / spu) * val;
  }
  if (lane == 0) atomicAdd(&scal[1], wacc);
}

// one block per sample s: argmax_n gumbel(s,n) + log(p1[n]) over valid list
__global__ __launch_bounds__(256) void k_sample(const int* __restrict__ vidx,
                                                const float* __restrict__ vlog,
                                                const int* __restrict__ counters,
                                                int* __restrict__ sampled) {
  __shared__ float sv[256];
  __shared__ int si[256];
  int s = blockIdx.x;
  int nv = counters[1];
  float best = -INFINITY;
  int bi = 0x7fffffff;
  u32 base = (u32)s * (u32)NN;
  for (int j = threadIdx.x; j < nv; j += 256) {
    int n = vidx[j];
    u32 bits;
#if PRNG_VARIANT == 1
    uint2 r = tf2x32(0u, base + (u32)n);
    bits = r.x ^ r.y;
#elif PRNG_VARIANT == 3
    uint2 r = tf2x32(0u, base + (u32)n);
    bits = r.x;
#else
    u32 i = base + (u32)n;
    if (s < 256) { uint2 r = tf2x32(i, i + HH); bits = r.x; }
    else         { uint2 r = tf2x32(i - HH, i); bits = r.y; }
#endif
    float g = gumbel_from_bits(bits) + vlog[j];
    if (g > best || (g == best && n < bi)) { best = g; bi = n; }
  }
  sv[threadIdx.x] = best;
  si[threadIdx.x] = bi;
  __syncthreads();
#pragma unroll
  for (int off = 128; off; off >>= 1) {
    if (threadIdx.x < off) {
      float ov = sv[threadIdx.x + off];
      int oi = si[threadIdx.x + off];
      if (ov > sv[threadIdx.x] || (ov == sv[threadIdx.x] && oi < si[threadIdx.x])) {
        sv[threadIdx.x] = ov; si[threadIdx.x] = oi;
      }
    }
    __syncthreads();
  }
  if (threadIdx.x == 0) sampled[s] = si[0];
}

__global__ void k_xu(const float* __restrict__ feat, const int* __restrict__ sampled,
                     float* __restrict__ out) {
  int s = blockIdx.x;
  int row = sampled[s];
  out[(size_t)s * DD + threadIdx.x] = feat[(size_t)row * DD + threadIdx.x];
}

__global__ void k_support(const float* __restrict__ adj, const float* __restrict__ s1p1,
                          const int* __restrict__ sampled, const float* __restrict__ scal,
                          float* __restrict__ out) {
  int s = blockIdx.x;   // 0..511
  int b = threadIdx.x;  // 0..255
  int idx = sampled[s];
  float denom = s1p1[idx] * (float)SS;
  out[(size_t)SS * DD + (size_t)b * SS + s] = adj[(size_t)b * NN + idx] / denom;
  if (s == 0 && b == 0) out[(size_t)SS * DD + (size_t)BB * SS] = scal[1] / (float)DD;
}

extern "C" void kernel_launch(void* const* d_in, const int* in_sizes, int n_in,
                              void* d_out, int out_size, void* d_ws, size_t ws_size,
                              hipStream_t stream) {
  const float* feat = (const float*)d_in[0];
  const float* adj  = (const float*)d_in[1];
  const float* w1   = (const float*)d_in[2];
  const float* w2   = (const float*)d_in[3];
  const int*   v    = (const int*)d_in[4];
  float* out = (float*)d_out;

  float* ws    = (float*)d_ws;
  float* fw2   = ws;                       // [NN]
  float* s1p1  = ws + (size_t)NN;          // [NN] s1 then p1 in place
  float* vlog  = ws + 2 * (size_t)NN;      // [NN] log(p1) for valid list
  int*   vidx  = (int*)(ws + 3 * (size_t)NN); // [NN]
  int*   mlist = (int*)(ws + 4 * (size_t)NN); // [NN]
  float* hw1   = ws + 5 * (size_t)NN;         // [256]
  float* means = ws + 5 * (size_t)NN + 256;   // [256]
  float* scal  = ws + 5 * (size_t)NN + 512;   // [16]: [0]=sum_p1 [1]=loss; ints at +2
  int*   counters = (int*)(scal + 2);         // [0]=n_mask(num_neis) [1]=n_valid
  int*   sampled  = (int*)(ws + 5 * (size_t)NN + 528); // [512]

  k_init<<<1, 256, 0, stream>>>(scal, means);
  k_dotw<<<NN / 4, 256, 0, stream>>>(feat, w2, fw2, nullptr, NN);
  k_dotw<<<BB / 4, 256, 0, stream>>>(feat, w1, hw1, v, BB);
  k_adj<<<(NN + 255) / 256, 256, 0, stream>>>(adj, fw2, hw1, s1p1, mlist, vidx, counters);
  k_fin<<<128, 256, 0, stream>>>(s1p1, vlog, vidx, counters, scal);
  k_means<<<256, 256, 0, stream>>>(feat, mlist, counters, means);
  k_loss<<<256, 256, 0, stream>>>(feat, means, s1p1, vidx, counters, scal);
  k_sample<<<SS, 256, 0, stream>>>(vidx, vlog, counters, sampled);
  k_xu<<<SS, 256, 0, stream>>>(feat, sampled, out);
  k_support<<<SS, 256, 0, stream>>>(adj, s1p1, sampled, scal, out);
}

// Round 3
// 282.702 us; speedup vs baseline: 1.3101x; 1.3101x over previous
//
#include <hip/hip_runtime.h>
#include <math.h>
#include <stdint.h>

#define NN 200000   // nodes
#define NQ 50000    // NN/4 column quads
#define DD 256      // feature dim
#define BB 256      // batch rows of adj
#define SS 512      // output samples

// PRNG: threefry_partitionable (modern JAX default): elem i -> tf(0, i), bits = out0 ^ out1
// (verified PASS in round 2)

typedef unsigned int u32;
typedef unsigned long long u64;

// ---------------- threefry2x32, key = (0,1)  (jax.random.key(1)) ----------------
__device__ __forceinline__ uint2 tf2x32(u32 x0, u32 x1) {
  const u32 ks0 = 0u, ks1 = 1u, ks2 = 0x1BD11BDBu;
  x0 += ks0; x1 += ks1;
#define TFR(r) { x0 += x1; x1 = (x1 << (r)) | (x1 >> (32 - (r))); x1 ^= x0; }
  TFR(13) TFR(15) TFR(26) TFR(6)
  x0 += ks1; x1 += ks2 + 1u;
  TFR(17) TFR(29) TFR(16) TFR(24)
  x0 += ks2; x1 += ks0 + 2u;
  TFR(13) TFR(15) TFR(26) TFR(6)
  x0 += ks0; x1 += ks1 + 3u;
  TFR(17) TFR(29) TFR(16) TFR(24)
  x0 += ks1; x1 += ks2 + 4u;
  TFR(13) TFR(15) TFR(26) TFR(6)
  x0 += ks2; x1 += ks0 + 5u;
#undef TFR
  return make_uint2(x0, x1);
}

__device__ __forceinline__ float gumbel_from_bits(u32 bits) {
  const float TINY = 1.17549435e-38f;
  float f = __uint_as_float((bits >> 9) | 0x3f800000u) - 1.0f; // [0,1)
  float x = f + TINY;
  x = fmaxf(TINY, x);
  return -logf(-logf(x));
}

// ---------------- kernels ----------------
// zero s1, umask words, means, scal/counters
__global__ void k_zero(float* __restrict__ s1, u32* __restrict__ umaskw,
                       float* __restrict__ means, float* __restrict__ scal) {
  int i = blockIdx.x * 256 + threadIdx.x;
  int stride = gridDim.x * 256;
  for (int j = i; j < NN; j += stride) s1[j] = 0.0f;
  for (int j = i; j < NQ; j += stride) umaskw[j] = 0u;
  if (i < 256) means[i] = 0.0f;
  if (i < 16) scal[i] = 0.0f;
}

// two rows per wave: dot(feat[row], w). rows==nullptr -> row=pair index (fw2); else gathered (hw1)
__global__ __launch_bounds__(256) void k_dotw(const float* __restrict__ feat,
                                              const float* __restrict__ w,
                                              float* __restrict__ outv,
                                              const int* __restrict__ rows,
                                              int nrows) {
  int wave = blockIdx.x * 4 + (threadIdx.x >> 6);
  int lane = threadIdx.x & 63;
  int r0 = wave * 2, r1 = r0 + 1;
  if (r0 >= nrows) return;
  float4 w4 = ((const float4*)w)[lane];
  int row0 = rows ? rows[r0] : r0;
  bool has1 = (r1 < nrows);
  int row1 = has1 ? (rows ? rows[r1] : r1) : row0;
  float4 fa = ((const float4*)(feat + (size_t)row0 * DD))[lane];
  float4 fb = ((const float4*)(feat + (size_t)row1 * DD))[lane];
  float d0 = fa.x * w4.x + fa.y * w4.y + fa.z * w4.z + fa.w * w4.w;
  float d1 = fb.x * w4.x + fb.y * w4.y + fb.z * w4.z + fb.w * w4.w;
#pragma unroll
  for (int off = 32; off; off >>= 1) {
    d0 += __shfl_down(d0, off);
    d1 += __shfl_down(d1, off);
  }
  if (lane == 0) {
    outv[r0] = d0;
    if (has1) outv[r1] = d1;
  }
}

// b-chunked column pass over adj: 8 chunks x 32 b. float4 columns, 8 loads in flight.
// umask flag via benign-race byte store; s1 accumulated via sparse atomicAdd.
__global__ __launch_bounds__(256) void k_adj_partial(const float* __restrict__ adj,
                                                     const float* __restrict__ fw2,
                                                     const float* __restrict__ hw1,
                                                     float* __restrict__ s1,
                                                     unsigned char* __restrict__ umask) {
  __shared__ float hs[BB];
  hs[threadIdx.x] = hw1[threadIdx.x];
  __syncthreads();
  int cb = blockIdx.x % 196;  // column block (1024 cols each)
  int ch = blockIdx.x / 196;  // b-chunk 0..7 (32 b each)
  int q = cb * 256 + threadIdx.x;
  if (q >= NQ) return;
  const float4* adj4 = (const float4*)adj;
  float4 fv = ((const float4*)fw2)[q];
  float csx = 0.f, csy = 0.f, csz = 0.f, csw = 0.f;
  float ssx = 0.f, ssy = 0.f, ssz = 0.f, ssw = 0.f;
  int b0 = ch * 32;
  for (int bb = 0; bb < 32; bb += 8) {
    float4 a[8];
#pragma unroll
    for (int k = 0; k < 8; ++k) a[k] = adj4[(size_t)(b0 + bb + k) * NQ + q];
#pragma unroll
    for (int k = 0; k < 8; ++k) {
      float h = hs[b0 + bb + k] + 1.0f;
      csx += a[k].x; csy += a[k].y; csz += a[k].z; csw += a[k].w;
      if (a[k].x > 0.f) ssx += a[k].x * fmaxf(h + fv.x, 0.f);
      if (a[k].y > 0.f) ssy += a[k].y * fmaxf(h + fv.y, 0.f);
      if (a[k].z > 0.f) ssz += a[k].z * fmaxf(h + fv.z, 0.f);
      if (a[k].w > 0.f) ssw += a[k].w * fmaxf(h + fv.w, 0.f);
    }
  }
  int n0 = q * 4;
  if (csx > 0.f) umask[n0 + 0] = 1;
  if (csy > 0.f) umask[n0 + 1] = 1;
  if (csz > 0.f) umask[n0 + 2] = 1;
  if (csw > 0.f) umask[n0 + 3] = 1;
  if (ssx > 0.f) atomicAdd(&s1[n0 + 0], ssx);
  if (ssy > 0.f) atomicAdd(&s1[n0 + 1], ssy);
  if (ssz > 0.f) atomicAdd(&s1[n0 + 2], ssz);
  if (ssw > 0.f) atomicAdd(&s1[n0 + 3], ssw);
}

// build compacted mask list (umask) and valid list (s1>0) + counts
__global__ __launch_bounds__(256) void k_adj_fin(const float* __restrict__ s1,
                                                 const unsigned char* __restrict__ umask,
                                                 int* __restrict__ mlist,
                                                 int* __restrict__ vidx,
                                                 int* __restrict__ counters) {
  int n = blockIdx.x * 256 + threadIdx.x;
  bool on = (n < NN);
  int lane = threadIdx.x & 63;
  {
    bool pred = on && (umask[on ? n : 0] != 0);
    u64 bm = __ballot(pred);
    int cnt = __popcll(bm);
    if (cnt) {
      int leader = __ffsll((u64)bm) - 1;
      int base = 0;
      if (lane == leader) base = atomicAdd(&counters[0], cnt);
      base = __shfl(base, leader);
      if (pred) mlist[base + __popcll(bm & ((1ull << lane) - 1ull))] = n;
    }
  }
  {
    bool pred = on && (s1[on ? n : 0] > 0.0f);
    u64 bm = __ballot(pred);
    int cnt = __popcll(bm);
    if (cnt) {
      int leader = __ffsll((u64)bm) - 1;
      int base = 0;
      if (lane == leader) base = atomicAdd(&counters[1], cnt);
      base = __shfl(base, leader);
      if (pred) vidx[base + __popcll(bm & ((1ull << lane) - 1ull))] = n;
    }
  }
}

// p1 = s1/num_neis (in place), vlog[j] = log(p1), sum_p1
__global__ void k_fin(float* __restrict__ s1p1, float* __restrict__ vlog,
                      const int* __restrict__ vidx, const int* __restrict__ counters,
                      float* __restrict__ scal) {
  int nv = counters[1];
  float nnf = (float)counters[0];
  float local = 0.0f;
  for (int j = blockIdx.x * blockDim.x + threadIdx.x; j < nv; j += gridDim.x * blockDim.x) {
    int n = vidx[j];
    float p = s1p1[n] / nnf;
    s1p1[n] = p;
    vlog[j] = logf(p);
    local += p;
  }
#pragma unroll
  for (int off = 32; off; off >>= 1) local += __shfl_down(local, off);
  if ((threadIdx.x & 63) == 0) atomicAdd(&scal[0], local);
}

// means[d] = sum over masked rows; wave-per-row float4, LDS pre-reduce, 1 atomic pass per block
__global__ __launch_bounds__(256) void k_means(const float* __restrict__ feat,
                                               const int* __restrict__ mlist,
                                               const int* __restrict__ counters,
                                               float* __restrict__ means) {
  __shared__ float part[4][DD];
  int nm = counters[0];
  int wv = threadIdx.x >> 6;
  int lane = threadIdx.x & 63;
  int wave = blockIdx.x * 4 + wv;
  int stride = gridDim.x * 4;
  float4 acc = {0.f, 0.f, 0.f, 0.f};
  for (int j = wave; j < nm; j += stride) {
    float4 f = ((const float4*)(feat + (size_t)mlist[j] * DD))[lane];
    acc.x += f.x; acc.y += f.y; acc.z += f.z; acc.w += f.w;
  }
  ((float4*)part[wv])[lane] = acc;
  __syncthreads();
  // 256 threads: each sums 4 partials for one d
  int d = threadIdx.x;
  float v = part[0][d] + part[1][d] + part[2][d] + part[3][d];
  atomicAdd(&means[d], v);
}

// loss_acc = sum over valid rows of p_u * ||f[row]-means||^2 (wave per row)
__global__ void k_loss(const float* __restrict__ feat, const float* __restrict__ means,
                       const float* __restrict__ s1p1, const int* __restrict__ vidx,
                       const int* __restrict__ counters, float* __restrict__ scal) {
  __shared__ float ms[DD];
  ms[threadIdx.x] = means[threadIdx.x];
  __syncthreads();
  int nv = counters[1];
  float spu = scal[0];
  int gw = blockIdx.x * 4 + (threadIdx.x >> 6);
  int tw = gridDim.x * 4;
  int lane = threadIdx.x & 63;
  float wacc = 0.0f;
  for (int j = gw; j < nv; j += tw) {
    int r = vidx[j];
    float4 f4 = ((const float4*)(feat + (size_t)r * DD))[lane];
    float4 m4 = ((const float4*)ms)[lane];
    float dx = f4.x - m4.x, dy = f4.y - m4.y, dz = f4.z - m4.z, dw = f4.w - m4.w;
    float val = dx * dx + dy * dy + dz * dz + dw * dw;
#pragma unroll
    for (int off = 32; off; off >>= 1) val += __shfl_down(val, off);
    if (lane == 0) wacc += (s1p1[r] / spu) * val;
  }
  if (lane == 0) atomicAdd(&scal[1], wacc);
}

// one block per sample s: argmax_n gumbel(s,n) + log(p1[n]) over valid list
__global__ __launch_bounds__(256) void k_sample(const int* __restrict__ vidx,
                                                const float* __restrict__ vlog,
                                                const int* __restrict__ counters,
                                                int* __restrict__ sampled) {
  __shared__ float sv[256];
  __shared__ int si[256];
  int s = blockIdx.x;
  int nv = counters[1];
  float best = -INFINITY;
  int bi = 0x7fffffff;
  u32 base = (u32)s * (u32)NN;
  for (int j = threadIdx.x; j < nv; j += 256) {
    int n = vidx[j];
    uint2 r = tf2x32(0u, base + (u32)n);
    u32 bits = r.x ^ r.y;
    float g = gumbel_from_bits(bits) + vlog[j];
    if (g > best || (g == best && n < bi)) { best = g; bi = n; }
  }
  sv[threadIdx.x] = best;
  si[threadIdx.x] = bi;
  __syncthreads();
#pragma unroll
  for (int off = 128; off; off >>= 1) {
    if (threadIdx.x < off) {
      float ov = sv[threadIdx.x + off];
      int oi = si[threadIdx.x + off];
      if (ov > sv[threadIdx.x] || (ov == sv[threadIdx.x] && oi < si[threadIdx.x])) {
        sv[threadIdx.x] = ov; si[threadIdx.x] = oi;
      }
    }
    __syncthreads();
  }
  if (threadIdx.x == 0) sampled[s] = si[0];
}

__global__ void k_xu(const float* __restrict__ feat, const int* __restrict__ sampled,
                     float* __restrict__ out) {
  int s = blockIdx.x;
  int row = sampled[s];
  out[(size_t)s * DD + threadIdx.x] = feat[(size_t)row * DD + threadIdx.x];
}

__global__ void k_support(const float* __restrict__ adj, const float* __restrict__ s1p1,
                          const int* __restrict__ sampled, const float* __restrict__ scal,
                          float* __restrict__ out) {
  int s = blockIdx.x;   // 0..511
  int b = threadIdx.x;  // 0..255
  int idx = sampled[s];
  float denom = s1p1[idx] * (float)SS;
  out[(size_t)SS * DD + (size_t)b * SS + s] = adj[(size_t)b * NN + idx] / denom;
  if (s == 0 && b == 0) out[(size_t)SS * DD + (size_t)BB * SS] = scal[1] / (float)DD;
}

extern "C" void kernel_launch(void* const* d_in, const int* in_sizes, int n_in,
                              void* d_out, int out_size, void* d_ws, size_t ws_size,
                              hipStream_t stream) {
  const float* feat = (const float*)d_in[0];
  const float* adj  = (const float*)d_in[1];
  const float* w1   = (const float*)d_in[2];
  const float* w2   = (const float*)d_in[3];
  const int*   v    = (const int*)d_in[4];
  float* out = (float*)d_out;

  float* ws    = (float*)d_ws;
  float* fw2   = ws;                          // [NN]
  float* s1p1  = ws + (size_t)NN;             // [NN] s1 then p1 in place
  float* vlog  = ws + 2 * (size_t)NN;         // [NN]
  int*   vidx  = (int*)(ws + 3 * (size_t)NN); // [NN]
  int*   mlist = (int*)(ws + 4 * (size_t)NN); // [NN]
  unsigned char* umask = (unsigned char*)(ws + 5 * (size_t)NN); // [NN] bytes (NQ float slots)
  float* tail  = ws + 5 * (size_t)NN + NQ;
  float* hw1   = tail;                        // [256]
  float* means = tail + 256;                  // [256]
  float* scal  = tail + 512;                  // [16]: [0]=sum_p1 [1]=loss; ints at +2
  int*   counters = (int*)(scal + 2);         // [0]=n_mask [1]=n_valid
  int*   sampled  = (int*)(tail + 528);       // [512]

  k_zero<<<512, 256, 0, stream>>>(s1p1, (u32*)umask, means, scal);
  k_dotw<<<NN / 8, 256, 0, stream>>>(feat, w2, fw2, nullptr, NN);
  k_dotw<<<BB / 8, 256, 0, stream>>>(feat, w1, hw1, v, BB);
  k_adj_partial<<<196 * 8, 256, 0, stream>>>(adj, fw2, hw1, s1p1, umask);
  k_adj_fin<<<(NN + 255) / 256, 256, 0, stream>>>(s1p1, umask, mlist, vidx, counters);
  k_fin<<<128, 256, 0, stream>>>(s1p1, vlog, vidx, counters, scal);
  k_means<<<128, 256, 0, stream>>>(feat, mlist, counters, means);
  k_loss<<<256, 256, 0, stream>>>(feat, means, s1p1, vidx, counters, scal);
  k_sample<<<SS, 256, 0, stream>>>(vidx, vlog, counters, sampled);
  k_xu<<<SS, 256, 0, stream>>>(feat, sampled, out);
  k_support<<<SS, 256, 0, stream>>>(adj, s1p1, sampled, scal, out);
}

// Round 4
// 262.885 us; speedup vs baseline: 1.4088x; 1.0754x over previous
//
#include <hip/hip_runtime.h>
#include <math.h>
#include <stdint.h>

#define NN 200000   // nodes
#define NQ 50000    // NN/4 column quads
#define DD 256      // feature dim
#define BB 256      // batch rows of adj
#define SS 512      // output samples

// PRNG: threefry_partitionable (modern JAX default): elem i -> tf(0, i), bits = out0 ^ out1
// (verified bit-exact PASS, absmax 0.0, rounds 2-3)

typedef unsigned int u32;
typedef unsigned long long u64;
typedef float f4 __attribute__((ext_vector_type(4)));

__device__ __forceinline__ f4 ldnt4(const float* p) {
  return __builtin_nontemporal_load((const f4*)p);
}

// ---------------- threefry2x32, key = (0,1)  (jax.random.key(1)) ----------------
__device__ __forceinline__ uint2 tf2x32(u32 x0, u32 x1) {
  const u32 ks0 = 0u, ks1 = 1u, ks2 = 0x1BD11BDBu;
  x0 += ks0; x1 += ks1;
#define TFR(r) { x0 += x1; x1 = (x1 << (r)) | (x1 >> (32 - (r))); x1 ^= x0; }
  TFR(13) TFR(15) TFR(26) TFR(6)
  x0 += ks1; x1 += ks2 + 1u;
  TFR(17) TFR(29) TFR(16) TFR(24)
  x0 += ks2; x1 += ks0 + 2u;
  TFR(13) TFR(15) TFR(26) TFR(6)
  x0 += ks0; x1 += ks1 + 3u;
  TFR(17) TFR(29) TFR(16) TFR(24)
  x0 += ks1; x1 += ks2 + 4u;
  TFR(13) TFR(15) TFR(26) TFR(6)
  x0 += ks2; x1 += ks0 + 5u;
#undef TFR
  return make_uint2(x0, x1);
}

__device__ __forceinline__ float gumbel_from_bits(u32 bits) {
  const float TINY = 1.17549435e-38f;
  float f = __uint_as_float((bits >> 9) | 0x3f800000u) - 1.0f; // [0,1)
  float x = f + TINY;
  x = fmaxf(TINY, x);
  return -logf(-logf(x));
}

// pack (gumbel g, index n) so u64-max == (argmax g, first-index tie-break)
__device__ __forceinline__ u64 pack_key(float g, int n) {
  u32 u = __float_as_uint(g);
  u32 m = (u & 0x80000000u) ? ~u : (u | 0x80000000u); // monotone order-preserving map
  return ((u64)m << 32) | (u32)(~(u32)n);             // larger ~n == smaller n wins ties
}

// ---------------- kernels ----------------
// zero s1, umask words, means, scal/counters, sample slots
__global__ void k_zero(float* __restrict__ s1, u32* __restrict__ umaskw,
                       float* __restrict__ means, float* __restrict__ scal,
                       u64* __restrict__ slots) {
  int i = blockIdx.x * 256 + threadIdx.x;
  int stride = gridDim.x * 256;
  for (int j = i; j < NN; j += stride) s1[j] = 0.0f;
  for (int j = i; j < NQ; j += stride) umaskw[j] = 0u;
  if (i < 256) means[i] = 0.0f;
  if (i < 16) scal[i] = 0.0f;
  if (i < SS) slots[i] = 0ull;
}

// four rows per wave: dot(feat[row], w). rows==nullptr -> streaming (nontemporal feat)
__global__ __launch_bounds__(256) void k_dotw(const float* __restrict__ feat,
                                              const float* __restrict__ w,
                                              float* __restrict__ outv,
                                              const int* __restrict__ rows,
                                              int nrows) {
  int wave = blockIdx.x * 4 + (threadIdx.x >> 6);
  int lane = threadIdx.x & 63;
  int r0 = wave * 4;
  if (r0 >= nrows) return;  // nrows divisible by 4 in both uses
  f4 w4 = ((const f4*)w)[lane];
  f4 f[4];
  if (rows) {
#pragma unroll
    for (int k = 0; k < 4; ++k)
      f[k] = ((const f4*)(feat + (size_t)rows[r0 + k] * DD))[lane];
  } else {
#pragma unroll
    for (int k = 0; k < 4; ++k)
      f[k] = ldnt4(feat + (size_t)(r0 + k) * DD + lane * 4);
  }
  float d[4];
#pragma unroll
  for (int k = 0; k < 4; ++k)
    d[k] = f[k].x * w4.x + f[k].y * w4.y + f[k].z * w4.z + f[k].w * w4.w;
#pragma unroll
  for (int off = 32; off; off >>= 1) {
#pragma unroll
    for (int k = 0; k < 4; ++k) d[k] += __shfl_down(d[k], off);
  }
  if (lane == 0) {
#pragma unroll
    for (int k = 0; k < 4; ++k) outv[r0 + k] = d[k];
  }
}

// b-chunked column pass over adj: 8 chunks x 32 b. float4 columns, 8 loads in flight.
__global__ __launch_bounds__(256) void k_adj_partial(const float* __restrict__ adj,
                                                     const float* __restrict__ fw2,
                                                     const float* __restrict__ hw1,
                                                     float* __restrict__ s1,
                                                     unsigned char* __restrict__ umask) {
  __shared__ float hs[BB];
  hs[threadIdx.x] = hw1[threadIdx.x];
  __syncthreads();
  int cb = blockIdx.x % 196;  // column block (1024 cols each)
  int ch = blockIdx.x / 196;  // b-chunk 0..7 (32 b each)
  int q = cb * 256 + threadIdx.x;
  if (q >= NQ) return;
  const float4* adj4 = (const float4*)adj;
  float4 fv = ((const float4*)fw2)[q];
  float csx = 0.f, csy = 0.f, csz = 0.f, csw = 0.f;
  float ssx = 0.f, ssy = 0.f, ssz = 0.f, ssw = 0.f;
  int b0 = ch * 32;
  for (int bb = 0; bb < 32; bb += 8) {
    float4 a[8];
#pragma unroll
    for (int k = 0; k < 8; ++k) a[k] = adj4[(size_t)(b0 + bb + k) * NQ + q];
#pragma unroll
    for (int k = 0; k < 8; ++k) {
      float h = hs[b0 + bb + k] + 1.0f;
      csx += a[k].x; csy += a[k].y; csz += a[k].z; csw += a[k].w;
      ssx += a[k].x * fmaxf(h + fv.x, 0.f);
      ssy += a[k].y * fmaxf(h + fv.y, 0.f);
      ssz += a[k].z * fmaxf(h + fv.z, 0.f);
      ssw += a[k].w * fmaxf(h + fv.w, 0.f);
    }
  }
  int n0 = q * 4;
  if (csx > 0.f) umask[n0 + 0] = 1;
  if (csy > 0.f) umask[n0 + 1] = 1;
  if (csz > 0.f) umask[n0 + 2] = 1;
  if (csw > 0.f) umask[n0 + 3] = 1;
  if (ssx > 0.f) atomicAdd(&s1[n0 + 0], ssx);
  if (ssy > 0.f) atomicAdd(&s1[n0 + 1], ssy);
  if (ssz > 0.f) atomicAdd(&s1[n0 + 2], ssz);
  if (ssw > 0.f) atomicAdd(&s1[n0 + 3], ssw);
}

// build compacted mask list (umask) and valid list (s1>0) + counts
__global__ __launch_bounds__(256) void k_adj_fin(const float* __restrict__ s1,
                                                 const unsigned char* __restrict__ umask,
                                                 int* __restrict__ mlist,
                                                 int* __restrict__ vidx,
                                                 int* __restrict__ counters) {
  int n = blockIdx.x * 256 + threadIdx.x;
  bool on = (n < NN);
  int lane = threadIdx.x & 63;
  {
    bool pred = on && (umask[on ? n : 0] != 0);
    u64 bm = __ballot(pred);
    int cnt = __popcll(bm);
    if (cnt) {
      int leader = __ffsll((u64)bm) - 1;
      int base = 0;
      if (lane == leader) base = atomicAdd(&counters[0], cnt);
      base = __shfl(base, leader);
      if (pred) mlist[base + __popcll(bm & ((1ull << lane) - 1ull))] = n;
    }
  }
  {
    bool pred = on && (s1[on ? n : 0] > 0.0f);
    u64 bm = __ballot(pred);
    int cnt = __popcll(bm);
    if (cnt) {
      int leader = __ffsll((u64)bm) - 1;
      int base = 0;
      if (lane == leader) base = atomicAdd(&counters[1], cnt);
      base = __shfl(base, leader);
      if (pred) vidx[base + __popcll(bm & ((1ull << lane) - 1ull))] = n;
    }
  }
}

// p1 = s1/num_neis (in place), vlog[j] = log(p1), sum_p1
__global__ void k_fin(float* __restrict__ s1p1, float* __restrict__ vlog,
                      const int* __restrict__ vidx, const int* __restrict__ counters,
                      float* __restrict__ scal) {
  int nv = counters[1];
  float nnf = (float)counters[0];
  float local = 0.0f;
  for (int j = blockIdx.x * blockDim.x + threadIdx.x; j < nv; j += gridDim.x * blockDim.x) {
    int n = vidx[j];
    float p = s1p1[n] / nnf;
    s1p1[n] = p;
    vlog[j] = logf(p);
    local += p;
  }
#pragma unroll
  for (int off = 32; off; off >>= 1) local += __shfl_down(local, off);
  if ((threadIdx.x & 63) == 0) atomicAdd(&scal[0], local);
}

// 2 blocks per sample: partial argmax over valid list, u64 atomicMax merge
__global__ __launch_bounds__(256) void k_sample(const int* __restrict__ vidx,
                                                const float* __restrict__ vlog,
                                                const int* __restrict__ counters,
                                                u64* __restrict__ slots) {
  __shared__ u64 sk[256];
  int s = blockIdx.x >> 1;
  int half = blockIdx.x & 1;
  int nv = counters[1];
  u64 best = 0ull;
  u32 base = (u32)s * (u32)NN;
#pragma unroll 2
  for (int j = half * 256 + threadIdx.x; j < nv; j += 512) {
    int n = vidx[j];
    uint2 r = tf2x32(0u, base + (u32)n);
    float g = gumbel_from_bits(r.x ^ r.y) + vlog[j];
    u64 key = pack_key(g, n);
    if (key > best) best = key;
  }
  sk[threadIdx.x] = best;
  __syncthreads();
#pragma unroll
  for (int off = 128; off; off >>= 1) {
    if (threadIdx.x < off) {
      u64 o = sk[threadIdx.x + off];
      if (o > sk[threadIdx.x]) sk[threadIdx.x] = o;
    }
    __syncthreads();
  }
  if (threadIdx.x == 0) atomicMax(&slots[s], sk[0]);
}

// means[d] = sum over masked rows; wave-per-row float4, LDS pre-reduce
__global__ __launch_bounds__(256) void k_means(const float* __restrict__ feat,
                                               const int* __restrict__ mlist,
                                               const int* __restrict__ counters,
                                               float* __restrict__ means) {
  __shared__ float part[4][DD];
  int nm = counters[0];
  int wv = threadIdx.x >> 6;
  int lane = threadIdx.x & 63;
  int wave = blockIdx.x * 4 + wv;
  int stride = gridDim.x * 4;
  float4 acc = {0.f, 0.f, 0.f, 0.f};
  for (int j = wave; j < nm; j += stride) {
    float4 f = ((const float4*)(feat + (size_t)mlist[j] * DD))[lane];
    acc.x += f.x; acc.y += f.y; acc.z += f.z; acc.w += f.w;
  }
  ((float4*)part[wv])[lane] = acc;
  __syncthreads();
  int d = threadIdx.x;
  float v = part[0][d] + part[1][d] + part[2][d] + part[3][d];
  atomicAdd(&means[d], v);
}

// loss_acc = sum over valid rows of p_u * ||f[row]-means||^2 (wave per row)
__global__ void k_loss(const float* __restrict__ feat, const float* __restrict__ means,
                       const float* __restrict__ s1p1, const int* __restrict__ vidx,
                       const int* __restrict__ counters, float* __restrict__ scal) {
  __shared__ float ms[DD];
  ms[threadIdx.x] = means[threadIdx.x];
  __syncthreads();
  int nv = counters[1];
  float spu = scal[0];
  int gw = blockIdx.x * 4 + (threadIdx.x >> 6);
  int tw = gridDim.x * 4;
  int lane = threadIdx.x & 63;
  float wacc = 0.0f;
  for (int j = gw; j < nv; j += tw) {
    int r = vidx[j];
    float4 f4 = ((const float4*)(feat + (size_t)r * DD))[lane];
    float4 m4 = ((const float4*)ms)[lane];
    float dx = f4.x - m4.x, dy = f4.y - m4.y, dz = f4.z - m4.z, dw = f4.w - m4.w;
    float val = dx * dx + dy * dy + dz * dz + dw * dw;
#pragma unroll
    for (int off = 32; off; off >>= 1) val += __shfl_down(val, off);
    if (lane == 0) wacc += (s1p1[r] / spu) * val;
  }
  if (lane == 0) atomicAdd(&scal[1], wacc);
}

// fused epilogue: blocks 0..255 copy x_u rows (2 samples each);
// blocks 256..511 write support row b (coalesced), gathering adj from L3
__global__ __launch_bounds__(512) void k_tail(const float* __restrict__ feat,
                                              const float* __restrict__ adj,
                                              const float* __restrict__ s1p1,
                                              const u64* __restrict__ slots,
                                              const float* __restrict__ scal,
                                              float* __restrict__ out) {
  int blk = blockIdx.x;
  if (blk < 256) {
    int s = blk * 2 + (threadIdx.x >> 8);
    int t = threadIdx.x & 255;
    int idx = (int)(~(u32)slots[s]);
    out[(size_t)s * DD + t] = feat[(size_t)idx * DD + t];
  } else {
    int b = blk - 256;
    int s = threadIdx.x;  // 0..511
    int idx = (int)(~(u32)slots[s]);
    float denom = s1p1[idx] * (float)SS;
    out[(size_t)SS * DD + (size_t)b * SS + s] = adj[(size_t)b * NN + idx] / denom;
    if (b == 255 && s == 0) out[(size_t)SS * DD + (size_t)BB * SS] = scal[1] / (float)DD;
  }
}

extern "C" void kernel_launch(void* const* d_in, const int* in_sizes, int n_in,
                              void* d_out, int out_size, void* d_ws, size_t ws_size,
                              hipStream_t stream) {
  const float* feat = (const float*)d_in[0];
  const float* adj  = (const float*)d_in[1];
  const float* w1   = (const float*)d_in[2];
  const float* w2   = (const float*)d_in[3];
  const int*   v    = (const int*)d_in[4];
  float* out = (float*)d_out;

  float* ws    = (float*)d_ws;
  float* fw2   = ws;                          // [NN]
  float* s1p1  = ws + (size_t)NN;             // [NN] s1 then p1 in place
  float* vlog  = ws + 2 * (size_t)NN;         // [NN]
  int*   vidx  = (int*)(ws + 3 * (size_t)NN); // [NN]
  int*   mlist = (int*)(ws + 4 * (size_t)NN); // [NN]
  unsigned char* umask = (unsigned char*)(ws + 5 * (size_t)NN); // [NN] bytes
  float* tail  = ws + 5 * (size_t)NN + NQ;
  float* hw1   = tail;                        // [256]
  float* means = tail + 256;                  // [256]
  float* scal  = tail + 512;                  // [16]: [0]=sum_p1 [1]=loss; ints at +2
  int*   counters = (int*)(scal + 2);         // [0]=n_mask [1]=n_valid
  u64*   slots = (u64*)(tail + 544);          // [512] u64 argmax slots (8B aligned)

  k_zero<<<512, 256, 0, stream>>>(s1p1, (u32*)umask, means, scal, slots);
  k_dotw<<<NN / 16, 256, 0, stream>>>(feat, w2, fw2, nullptr, NN);
  k_dotw<<<BB / 16, 256, 0, stream>>>(feat, w1, hw1, v, BB);
  k_adj_partial<<<196 * 8, 256, 0, stream>>>(adj, fw2, hw1, s1p1, umask);
  k_adj_fin<<<(NN + 255) / 256, 256, 0, stream>>>(s1p1, umask, mlist, vidx, counters);
  k_fin<<<128, 256, 0, stream>>>(s1p1, vlog, vidx, counters, scal);
  k_sample<<<SS * 2, 256, 0, stream>>>(vidx, vlog, counters, slots);
  k_means<<<128, 256, 0, stream>>>(feat, mlist, counters, means);
  k_loss<<<256, 256, 0, stream>>>(feat, means, s1p1, vidx, counters, scal);
  k_tail<<<512, 512, 0, stream>>>(feat, adj, s1p1, slots, scal, out);
}